// Round 6
// baseline (125.547 us; speedup 1.0000x reference)
//
#include <hip/hip_runtime.h>
#include <hip/hip_cooperative_groups.h>
#include <math.h>

namespace cg = cooperative_groups;

#define N_A 64
#define N_B 128
#define N_C 128
#define D_IN 256
#define D_H 32
#define NHEADS 4
#define DMODEL (D_H * NHEADS)   // 128

// Workspace layout (float offsets)
#define OFF_Q    0                            // 8192
#define OFF_KB   (OFF_Q   + N_A*DMODEL)       // 16384
#define OFF_KC   (OFF_KB  + N_B*DMODEL)
#define OFF_VB   (OFF_KC  + N_C*DMODEL)
#define OFF_VC   (OFF_VB  + N_B*DMODEL)
#define OFF_EAB  (OFF_VC  + N_C*DMODEL)       // exp(sab) [ah][b]   32768
#define OFF_EAC  (OFF_EAB + N_A*NHEADS*N_B)   // exp(sac) [ah][c]   32768
#define OFF_EBC  (OFF_EAC + N_A*NHEADS*N_C)   // exp(sbc) [h][b][c] 65536
#define OFF_PB   (OFF_EBC + NHEADS*N_B*N_C)   // [b][h][kk]         2048
#define OFF_PC   (OFF_PB  + N_B*NHEADS*4)     // diag PCX [h][cc]   512
#define OFF_U    (OFF_PC  + NHEADS*N_C)       // U [ah][b]          32768

#define SCALE 0.17677669529663687f  // 1/sqrt(32)

// ============ Phase 1: projections, 2 rows/thread, 4-way k-split ============
// tid < 147456: r2 = tid>>9 (288 two-row groups), ks = (tid>>7)&3, col = tid&127
__device__ inline void phase1(int tid, int t,
    const float* __restrict__ Ha, const float* __restrict__ Hb,
    const float* __restrict__ Hc, const float* __restrict__ Wq,
    const float* __restrict__ Wk, const float* __restrict__ Wv,
    float* __restrict__ ws) {
  __shared__ float part[2 * 4 * 2 * 128];   // [r2loc][ks][row01][col] 8KB
  const int r2  = tid >> 9;
  const int ks  = (tid >> 7) & 3;
  const int col = tid & 127;

  const float* X; const float* W; float* Y; int r;
  {
    const int row = r2 * 2;
    if (row < 64)       { X = Ha; W = Wq; Y = ws + OFF_Q;  r = row; }
    else if (row < 192) { X = Hb; W = Wk; Y = ws + OFF_KB; r = row - 64; }
    else if (row < 320) { X = Hc; W = Wk; Y = ws + OFF_KC; r = row - 192; }
    else if (row < 448) { X = Hb; W = Wv; Y = ws + OFF_VB; r = row - 320; }
    else                { X = Hc; W = Wv; Y = ws + OFF_VC; r = row - 448; }
  }
  const float* x0 = X + r * D_IN;
  const float* x1 = x0 + D_IN;
  const int i0 = ks * 64;
  float acc0 = 0.0f, acc1 = 0.0f;
  #pragma unroll 8
  for (int i = 0; i < 64; ++i) {
    const float w = W[(i0 + i) * DMODEL + col];
    acc0 = fmaf(x0[i0 + i], w, acc0);
    acc1 = fmaf(x1[i0 + i], w, acc1);
  }
  const int rl = t >> 9;                      // 0..1 within block
  part[((rl * 4 + ks) * 2 + 0) * 128 + col] = acc0;
  part[((rl * 4 + ks) * 2 + 1) * 128 + col] = acc1;
  __syncthreads();
  if (ks == 0) {
    float f0 = 0.0f, f1 = 0.0f;
    #pragma unroll
    for (int k = 0; k < 4; ++k) {
      f0 += part[((rl * 4 + k) * 2 + 0) * 128 + col];
      f1 += part[((rl * 4 + k) * 2 + 1) * 128 + col];
    }
    Y[r * DMODEL + col]       = f0;
    Y[(r + 1) * DMODEL + col] = f1;
  }
}

// ============ Phase 2: E-scores (exp, no max shift) + pb + pc-diag ==========
__device__ inline void phase2(int idx, const float* __restrict__ fcw,
                              float* __restrict__ ws) {
  if (idx < 32768) {
    int b = idx & 127; int ah = idx >> 7; int a = ah >> 2; int h = ah & 3;
    const float4* q = (const float4*)(ws + OFF_Q  + a * DMODEL + h * D_H);
    const float4* k = (const float4*)(ws + OFF_KB + b * DMODEL + h * D_H);
    float acc = 0.0f;
    #pragma unroll
    for (int d = 0; d < 8; ++d) {
      float4 qv = q[d], kv = k[d];
      acc = fmaf(qv.x, kv.x, fmaf(qv.y, kv.y, fmaf(qv.z, kv.z, fmaf(qv.w, kv.w, acc))));
    }
    ws[OFF_EAB + idx] = __expf(acc * SCALE);
  } else if (idx < 65536) {
    int j = idx - 32768;
    int c = j & 127; int ah = j >> 7; int a = ah >> 2; int h = ah & 3;
    const float4* q = (const float4*)(ws + OFF_Q  + a * DMODEL + h * D_H);
    const float4* k = (const float4*)(ws + OFF_KC + c * DMODEL + h * D_H);
    float acc = 0.0f;
    #pragma unroll
    for (int d = 0; d < 8; ++d) {
      float4 qv = q[d], kv = k[d];
      acc = fmaf(qv.x, kv.x, fmaf(qv.y, kv.y, fmaf(qv.z, kv.z, fmaf(qv.w, kv.w, acc))));
    }
    ws[OFF_EAC + j] = __expf(acc * SCALE);
  } else if (idx < 131072) {
    int j = idx - 65536;               // (h*128+b)*128 + c
    int c = j & 127; int hb = j >> 7; int h = hb >> 7; int b = hb & 127;
    const float4* kb = (const float4*)(ws + OFF_KB + b * DMODEL + h * D_H);
    const float4* kc = (const float4*)(ws + OFF_KC + c * DMODEL + h * D_H);
    float acc = 0.0f;
    #pragma unroll
    for (int d = 0; d < 8; ++d) {
      float4 xv = kb[d], yv = kc[d];
      acc = fmaf(xv.x, yv.x, fmaf(xv.y, yv.y, fmaf(xv.z, yv.z, fmaf(xv.w, yv.w, acc))));
    }
    ws[OFF_EBC + j] = __expf(acc * SCALE);
  } else if (idx < 133120) {
    int j = idx - 131072;              // pb[(b*4+h)*4+kk]
    int kk = j & 3; int h = (j >> 2) & 3; int b = j >> 4;
    const float* v = ws + OFF_VB + b * DMODEL + h * D_H;
    const float* w = fcw + kk * D_H;
    float acc = 0.0f;
    #pragma unroll
    for (int d = 0; d < D_H; ++d) acc = fmaf(v[d], w[d], acc);
    ws[OFF_PB + j] = acc;
  } else if (idx < 133632) {
    int j = idx - 133120;              // pc-diag: h = j&3, cc = j>>2
    int h = j & 3; int cc = j >> 2;
    const float* v = ws + OFF_VC + cc * DMODEL + h * D_H;
    const float* w = fcw + (cc & 3) * D_H;
    float acc = 0.0f;
    #pragma unroll
    for (int d = 0; d < D_H; ++d) acc = fmaf(v[d], w[d], acc);
    ws[OFF_PC + h * N_C + cc] = acc;   // PCX[h][cc]
  }
}

// ============ Phase 3: U[ah][b] = sum_c Ebc[h,b,c]*Eac[ah,c], quad k-split ==
__device__ inline void phase3(int tid, float* __restrict__ ws) {
  const int u  = tid >> 2;             // < 32768
  const int ks = tid & 3;
  const int ah = u >> 7;
  const int b  = u & 127;
  const int h  = ah & 3;
  const float4* eac = (const float4*)(ws + OFF_EAC + ah * N_C + ks * 32);
  const float4* ebc = (const float4*)(ws + OFF_EBC + (h * N_B + b) * N_C + ks * 32);
  float v = 0.0f;
  #pragma unroll
  for (int i = 0; i < 8; ++i) {
    float4 ev = ebc[i], av = eac[i];
    v = fmaf(ev.x, av.x, fmaf(ev.y, av.y, fmaf(ev.z, av.z, fmaf(ev.w, av.w, v))));
  }
  v += __shfl_xor(v, 1);
  v += __shfl_xor(v, 2);
  if (ks == 0) ws[OFF_U + u] = v;
}

// ============ Phase 4: Z reduce + 4096 outputs per (a,h) block ==============
__device__ inline void phase4(int ah, int t, const float* __restrict__ ws,
                              const float* __restrict__ fcb,
                              float* __restrict__ out) {
  __shared__ float red[4];
  const int h = ah & 3;
  const int a = ah >> 2;
  // Z[ah] = sum_b Eab[ah,b] * U[ah,b]
  if (t < 128) {
    float v = ws[OFF_EAB + ah * N_B + t] * ws[OFF_U + ah * N_B + t];
    #pragma unroll
    for (int o = 32; o > 0; o >>= 1) v += __shfl_down(v, o, 64);
    if ((t & 63) == 0) red[t >> 6] = v;
  }
  __syncthreads();
  if (t == 0) red[2] = 1.0f / (red[0] + red[1]);
  __syncthreads();
  const float zi = red[2];
  const float fb = fcb[0];

  // outputs: b = h*32 + (t>>5), c = 4*(t&31) + j
  const int b_loc = t >> 5;
  const int c0    = (t & 31) * 4;
  const int b     = h * 32 + b_loc;
  const int bb    = (b_loc << 2) | (c0 >> 5);
  const float eabz = ws[OFF_EAB + ah * N_B + bb] * zi;
  const float4 pb4 = *(const float4*)(ws + OFF_PB + bb * 16 + h * 4);

  float4 res;
  float* rp = (float*)&res;
  #pragma unroll
  for (int j = 0; j < 4; ++j) {
    const int c    = c0 + j;
    const int base = (c & 31) << 2;
    const float4 ebc4 = *(const float4*)(ws + OFF_EBC + (h * N_B + bb) * N_C + base);
    const float4 eac4 = *(const float4*)(ws + OFF_EAC + ah * N_C + base);
    const float4 pcx4 = *(const float4*)(ws + OFF_PC + h * N_C + base);
    float acc = eac4.x * (ebc4.x * (pb4.x + pcx4.x));
    acc = fmaf(eac4.y, ebc4.y * (pb4.y + pcx4.y), acc);
    acc = fmaf(eac4.z, ebc4.z * (pb4.z + pcx4.z), acc);
    acc = fmaf(eac4.w, ebc4.w * (pb4.w + pcx4.w), acc);
    const float x = fmaf(acc, eabz, fb);
    rp[j] = 1.0f / (1.0f + __expf(-x));
  }
  *(float4*)(out + a * (N_B * N_C) + b * N_C + c0) = res;
}

// ============ Fused cooperative kernel: 256 blocks x 1024 threads ===========
__global__ __launch_bounds__(1024, 4) void fused_kernel(
    const float* __restrict__ Ha, const float* __restrict__ Hb,
    const float* __restrict__ Hc, const float* __restrict__ Wq,
    const float* __restrict__ Wk, const float* __restrict__ Wv,
    const float* __restrict__ fcw, const float* __restrict__ fcb,
    float* __restrict__ out, float* __restrict__ ws)
{
  cg::grid_group grid = cg::this_grid();
  const int t   = threadIdx.x;
  const int bid = blockIdx.x;
  const int tid = bid * 1024 + t;

  if (bid < 144) phase1(tid, t, Ha, Hb, Hc, Wq, Wk, Wv, ws);
  grid.sync();
  if (bid < 131) phase2(tid, fcw, ws);
  grid.sync();
  if (bid < 128) phase3(tid, ws);
  grid.sync();
  phase4(bid, t, ws, fcb, out);
}

// ============ Fallback: same phases as separate kernels =====================
__global__ __launch_bounds__(1024) void k1(
    const float* __restrict__ Ha, const float* __restrict__ Hb,
    const float* __restrict__ Hc, const float* __restrict__ Wq,
    const float* __restrict__ Wk, const float* __restrict__ Wv,
    float* __restrict__ ws) {
  phase1(blockIdx.x * 1024 + threadIdx.x, threadIdx.x, Ha, Hb, Hc, Wq, Wk, Wv, ws);
}
__global__ __launch_bounds__(1024) void k2(
    const float* __restrict__ fcw, float* __restrict__ ws) {
  phase2(blockIdx.x * 1024 + threadIdx.x, fcw, ws);
}
__global__ __launch_bounds__(1024) void k3(float* __restrict__ ws) {
  phase3(blockIdx.x * 1024 + threadIdx.x, ws);
}
__global__ __launch_bounds__(1024) void k4(
    const float* __restrict__ ws, const float* __restrict__ fcb,
    float* __restrict__ out) {
  phase4(blockIdx.x, threadIdx.x, ws, fcb, out);
}

extern "C" void kernel_launch(void* const* d_in, const int* in_sizes, int n_in,
                              void* d_out, int out_size, void* d_ws, size_t ws_size,
                              hipStream_t stream) {
  const float* Ha  = (const float*)d_in[0];
  const float* Hb  = (const float*)d_in[1];
  const float* Hc  = (const float*)d_in[2];
  const float* Wq  = (const float*)d_in[3];
  const float* Wk  = (const float*)d_in[4];
  const float* Wv  = (const float*)d_in[5];
  const float* fcw = (const float*)d_in[6];
  const float* fcb = (const float*)d_in[7];
  float* out = (float*)d_out;
  float* ws  = (float*)d_ws;

  void* args[] = { &Ha, &Hb, &Hc, &Wq, &Wk, &Wv, &fcw, &fcb, &out, &ws };
  hipError_t e = hipLaunchCooperativeKernel((const void*)fused_kernel,
                                            dim3(256), dim3(1024), args, 0, stream);
  if (e != hipSuccess) {
    // Cooperative launch rejected (silent no-op in capture) -> classic pipeline.
    k1<<<144, 1024, 0, stream>>>(Ha, Hb, Hc, Wq, Wk, Wv, ws);
    k2<<<131, 1024, 0, stream>>>(fcw, ws);
    k3<<<128, 1024, 0, stream>>>(ws);
    k4<<<256, 1024, 0, stream>>>(ws, fcb, out);
  }
}

// Round 7
// 26.325 us; speedup vs baseline: 4.7691x; 4.7691x over previous
//
#include <hip/hip_runtime.h>
#include <math.h>

#define N_A 64
#define N_B 128
#define N_C 128
#define D_IN 256
#define D_H 32
#define NHEADS 4
#define DMODEL (D_H * NHEADS)   // 128

// Workspace layout (float offsets)
#define OFF_Q    0
#define OFF_KB   (OFF_Q   + N_A*DMODEL)
#define OFF_KC   (OFF_KB  + N_B*DMODEL)
#define OFF_VB   (OFF_KC  + N_C*DMODEL)
#define OFF_VC   (OFF_VB  + N_B*DMODEL)
#define OFF_PB   (OFF_VC  + N_C*DMODEL)      // [b][h][kk]  2048
#define OFF_PC   (OFF_PB  + N_B*NHEADS*4)    // diag PCX [h][cc] 512

#define SCALE 0.17677669529663687f  // 1/sqrt(32)

__device__ __forceinline__ float dot4(float4 a, float4 b) {
  return fmaf(a.x, b.x, fmaf(a.y, b.y, fmaf(a.z, b.z, a.w * b.w)));
}

// XOR-swizzled index into a [128][32] float LDS tile: spreads rows 8-apart
// across 16B slots so 16-lane column reads are conflict-free.
__device__ __forceinline__ int kswz(int row, int d) {
  return (row * 32 + d) ^ (((row >> 3) & 7) << 2);
}

// ============ K1: projections (4 rows/block) + pb + pcx tail ================
// 144 blocks x 1024 threads. tid>>9 = two-row group; ks = 4-way k split.
__global__ __launch_bounds__(1024) void k1(
    const float* __restrict__ Ha, const float* __restrict__ Hb,
    const float* __restrict__ Hc, const float* __restrict__ Wq,
    const float* __restrict__ Wk, const float* __restrict__ Wv,
    const float* __restrict__ fcw, float* __restrict__ ws) {
  __shared__ float part[2 * 4 * 2 * 128];   // [rl][ks][row01][col]
  __shared__ float rowsL[4][128];           // final Y rows of this block
  const int t   = threadIdx.x;
  const int tid = blockIdx.x * 1024 + t;
  const int r2  = tid >> 9;                 // two-row group id (0..287)
  const int ks  = (t >> 7) & 3;
  const int col = t & 127;
  const int rl  = t >> 9;                   // 0..1 local group

  const float* X; const float* W; float* Y; int r;
  {
    const int row = r2 * 2;
    if (row < 64)       { X = Ha; W = Wq; Y = ws + OFF_Q;  r = row; }
    else if (row < 192) { X = Hb; W = Wk; Y = ws + OFF_KB; r = row - 64; }
    else if (row < 320) { X = Hc; W = Wk; Y = ws + OFF_KC; r = row - 192; }
    else if (row < 448) { X = Hb; W = Wv; Y = ws + OFF_VB; r = row - 320; }
    else                { X = Hc; W = Wv; Y = ws + OFF_VC; r = row - 448; }
  }
  const float* x0 = X + r * D_IN;
  const float* x1 = x0 + D_IN;
  const int i0 = ks * 64;
  float acc0 = 0.0f, acc1 = 0.0f;
  #pragma unroll 8
  for (int i = 0; i < 64; ++i) {
    const float w = W[(i0 + i) * DMODEL + col];
    acc0 = fmaf(x0[i0 + i], w, acc0);
    acc1 = fmaf(x1[i0 + i], w, acc1);
  }
  part[((rl * 4 + ks) * 2 + 0) * 128 + col] = acc0;
  part[((rl * 4 + ks) * 2 + 1) * 128 + col] = acc1;
  __syncthreads();
  if (ks == 0) {
    float f0 = 0.0f, f1 = 0.0f;
    #pragma unroll
    for (int k = 0; k < 4; ++k) {
      f0 += part[((rl * 4 + k) * 2 + 0) * 128 + col];
      f1 += part[((rl * 4 + k) * 2 + 1) * 128 + col];
    }
    Y[r * DMODEL + col]       = f0;
    Y[(r + 1) * DMODEL + col] = f1;
    rowsL[rl * 2 + 0][col] = f0;
    rowsL[rl * 2 + 1][col] = f1;
  }
  __syncthreads();

  // pb[b][h][kk] for Vb rows; pcx[h][cc] (kk = cc&3) for Vc rows.
  if (t < 64) {
    const int lr = t >> 4, e = t & 15, hh = e >> 2, kk = e & 3;
    const int row = blockIdx.x * 4 + lr;
    if (row >= 320) {
      float s = 0.0f;
      #pragma unroll
      for (int d = 0; d < D_H; ++d)
        s = fmaf(rowsL[lr][hh * D_H + d], fcw[kk * D_H + d], s);
      if (row < 448) {
        const int b = row - 320;
        ws[OFF_PB + (b * 4 + hh) * 4 + kk] = s;
      } else {
        const int cc = row - 448;
        if (kk == (cc & 3)) ws[OFF_PC + hh * N_C + cc] = s;
      }
    }
  }
}

// ============ K2: per-(a,h) block: E-scores + U + Z + output ================
// 256 blocks x 512 threads; everything after staging lives in LDS.
__global__ __launch_bounds__(512) void k2(
    const float* __restrict__ ws, const float* __restrict__ fcb,
    float* __restrict__ out) {
  __shared__ float KbL[128 * 32];           // swizzled [b][d]
  __shared__ float KcL[128 * 32];           // swizzled [c][d]
  __shared__ float EbcL[128 * 128];         // plain [b][c]
  __shared__ float qaL[32];
  __shared__ float EabL[128], EacL[128], UL[128];
  __shared__ float red[4];

  const int t = threadIdx.x;
  const int a = blockIdx.x >> 2;
  const int h = blockIdx.x & 3;

  // --- stage Kb, Kc h-slices (+ qa) ---
  {
    const int d = t & 31, r0 = t >> 5;      // r0 in [0,16)
    #pragma unroll
    for (int p = 0; p < 8; ++p) {
      const int r = r0 + p * 16;
      KbL[kswz(r, d)] = ws[OFF_KB + r * DMODEL + h * D_H + d];
      KcL[kswz(r, d)] = ws[OFF_KC + r * DMODEL + h * D_H + d];
    }
    if (t < 32) qaL[t] = ws[OFF_Q + a * DMODEL + h * D_H + t];
  }
  __syncthreads();

  // --- Eab[b], Eac[c]: 4 threads per row, quad shuffle-reduce ---
  {
    const int r = t >> 2, part = t & 3, d0 = part * 8;
    const float4 q0 = *(const float4*)&qaL[d0];
    const float4 q1 = *(const float4*)&qaL[d0 + 4];
    float4 x0 = *(const float4*)&KbL[kswz(r, d0)];
    float4 x1 = *(const float4*)&KbL[kswz(r, d0 + 4)];
    float s = dot4(q0, x0) + dot4(q1, x1);
    s += __shfl_xor(s, 1); s += __shfl_xor(s, 2);
    if (part == 0) EabL[r] = __expf(s * SCALE);
    x0 = *(const float4*)&KcL[kswz(r, d0)];
    x1 = *(const float4*)&KcL[kswz(r, d0 + 4)];
    s = dot4(q0, x0) + dot4(q1, x1);
    s += __shfl_xor(s, 1); s += __shfl_xor(s, 2);
    if (part == 0) EacL[r] = __expf(s * SCALE);
  }

  // --- Ebc plane: 8x8 register-tiled outer-product GEMM, t<256 ---
  if (t < 256) {
    const int b0 = (t >> 4) * 8, c0 = (t & 15) * 8;
    float acc[8][8];
    #pragma unroll
    for (int i = 0; i < 8; ++i)
      #pragma unroll
      for (int j = 0; j < 8; ++j) acc[i][j] = 0.0f;

    #pragma unroll
    for (int d0 = 0; d0 < 32; d0 += 4) {
      float4 cv[8];
      #pragma unroll
      for (int j = 0; j < 8; ++j) cv[j] = *(const float4*)&KcL[kswz(c0 + j, d0)];
      #pragma unroll
      for (int i = 0; i < 8; ++i) {
        const float4 bv = *(const float4*)&KbL[kswz(b0 + i, d0)];
        #pragma unroll
        for (int j = 0; j < 8; ++j) acc[i][j] += dot4(bv, cv[j]);
      }
    }
    #pragma unroll
    for (int i = 0; i < 8; ++i)
      #pragma unroll
      for (int j = 0; j < 8; ++j)
        EbcL[(b0 + i) * 128 + c0 + j] = __expf(acc[i][j] * SCALE);
  }
  __syncthreads();

  // --- U[b] = sum_c Ebc[b][c] * Eac[c]: 4 threads per b ---
  {
    const int b = t >> 2, part = t & 3, cb = part * 32;
    float s = 0.0f;
    #pragma unroll
    for (int k = 0; k < 8; ++k) {
      const float4 e  = *(const float4*)&EbcL[b * 128 + cb + k * 4];
      const float4 av = *(const float4*)&EacL[cb + k * 4];
      s += dot4(e, av);
    }
    s += __shfl_xor(s, 1); s += __shfl_xor(s, 2);
    if (part == 0) UL[b] = s;
  }
  __syncthreads();

  // --- Z = sum_b Eab[b] * U[b] ---
  if (t < 128) {
    float v = EabL[t] * UL[t];
    #pragma unroll
    for (int o = 32; o > 0; o >>= 1) v += __shfl_down(v, o, 64);
    if ((t & 63) == 0) red[t >> 6] = v;
  }
  __syncthreads();
  if (t == 0) red[2] = 1.0f / (red[0] + red[1]);
  __syncthreads();
  const float zi = red[2];
  const float fb = fcb[0];

  // --- output: 1024 float4-quads, 2 per thread ---
  #pragma unroll
  for (int q = 0; q < 2; ++q) {
    const int qid   = t + q * 512;          // < 1024
    const int b_loc = qid >> 5;             // 0..31
    const int c0v   = (qid & 31) * 4;       // 0..124
    const int b     = h * 32 + b_loc;
    const int bb    = (b_loc << 2) | (c0v >> 5);
    const int base  = (c0v & 31) << 2;

    const float eabz  = EabL[bb] * zi;
    const float4 ebc4 = *(const float4*)&EbcL[bb * 128 + base];
    const float4 eac4 = *(const float4*)&EacL[base];
    const float4 pb4  = *(const float4*)(ws + OFF_PB + bb * 16 + h * 4);
    const float4 pcx4 = *(const float4*)(ws + OFF_PC + h * N_C + base);

    float accv = eac4.x * (ebc4.x * (pb4.x + pcx4.x));
    accv = fmaf(eac4.y, ebc4.y * (pb4.y + pcx4.y), accv);
    accv = fmaf(eac4.z, ebc4.z * (pb4.z + pcx4.z), accv);
    accv = fmaf(eac4.w, ebc4.w * (pb4.w + pcx4.w), accv);
    const float x = fmaf(accv, eabz, fb);

    float4 res;
    res.x = 1.0f / (1.0f + __expf(-x));
    // recompute per lane-element: do all 4 properly
    // (scalarized below for clarity/correctness)
    float rr[4];
    rr[0] = res.x;
    {
      // elements 1..3 of the quad share (bb, base) per the index algebra:
      // cc = base + kk varies with kk only, which is exactly the float4 lanes.
      // The value above already summed kk=0..3 —— this IS the single output
      // for (b, c0v). The quad spans c = c0v..c0v+3, each with its own sums.
    }
    // NOTE: each c in the quad has different bb/base only via c>>5 and c&31;
    // within a 4-aligned quad c0v..c0v+3, (c>>5) and ((c&31)<<2) are NOT
    // constant-safe in general — but c0v is 4-aligned and c0v..c0v+3 share
    // c>>5 (since c0v%32 <= 28) and base advances by 4 each step... recompute
    // honestly per element:
    #pragma unroll
    for (int j = 1; j < 4; ++j) {
      const int c    = c0v + j;
      const int bbj  = (b_loc << 2) | (c >> 5);
      const int bsj  = (c & 31) << 2;
      const float eabzj  = EabL[bbj] * zi;
      const float4 e4 = *(const float4*)&EbcL[bbj * 128 + bsj];
      const float4 a4 = *(const float4*)&EacL[bsj];
      const float4 p4 = *(const float4*)(ws + OFF_PB + bbj * 16 + h * 4);
      const float4 x4 = *(const float4*)(ws + OFF_PC + h * N_C + bsj);
      float av = a4.x * (e4.x * (p4.x + x4.x));
      av = fmaf(a4.y, e4.y * (p4.y + x4.y), av);
      av = fmaf(a4.z, e4.z * (p4.z + x4.z), av);
      av = fmaf(a4.w, e4.w * (p4.w + x4.w), av);
      const float xj = fmaf(av, eabzj, fb);
      rr[j] = 1.0f / (1.0f + __expf(-xj));
    }
    res.x = rr[0]; res.y = rr[1]; res.z = rr[2]; res.w = rr[3];
    *(float4*)(out + a * (N_B * N_C) + b * N_C + c0v) = res;
  }
}

extern "C" void kernel_launch(void* const* d_in, const int* in_sizes, int n_in,
                              void* d_out, int out_size, void* d_ws, size_t ws_size,
                              hipStream_t stream) {
  const float* Ha  = (const float*)d_in[0];
  const float* Hb  = (const float*)d_in[1];
  const float* Hc  = (const float*)d_in[2];
  const float* Wq  = (const float*)d_in[3];
  const float* Wk  = (const float*)d_in[4];
  const float* Wv  = (const float*)d_in[5];
  const float* fcw = (const float*)d_in[6];
  const float* fcb = (const float*)d_in[7];
  float* out = (float*)d_out;
  float* ws  = (float*)d_ws;

  k1<<<144, 1024, 0, stream>>>(Ha, Hb, Hc, Wq, Wk, Wv, fcw, ws);
  k2<<<256, 512, 0, stream>>>(ws, fcb, out);
}

// Round 8
// 25.248 us; speedup vs baseline: 4.9726x; 1.0427x over previous
//
#include <hip/hip_runtime.h>
#include <math.h>

#define N_A 64
#define N_B 128
#define N_C 128
#define D_IN 256
#define D_H 32
#define NHEADS 4
#define DMODEL (D_H * NHEADS)   // 128

// Workspace layout (float offsets)
#define OFF_Q    0
#define OFF_KB   (OFF_Q   + N_A*DMODEL)
#define OFF_KC   (OFF_KB  + N_B*DMODEL)
#define OFF_VB   (OFF_KC  + N_C*DMODEL)
#define OFF_VC   (OFF_VB  + N_B*DMODEL)
#define OFF_PB   (OFF_VC  + N_C*DMODEL)      // [b][h][kk]  2048
#define OFF_PC   (OFF_PB  + N_B*NHEADS*4)    // diag PCX [h][cc] 512

#define SCALE 0.17677669529663687f  // 1/sqrt(32)

__device__ __forceinline__ float dot4(float4 a, float4 b) {
  return fmaf(a.x, b.x, fmaf(a.y, b.y, fmaf(a.z, b.z, a.w * b.w)));
}

// K-tile swizzle ([128][32] floats): spreads row-groups across 16B slots.
__device__ __forceinline__ int kswz(int row, int d) {
  return (row * 32 + d) ^ (((row >> 3) & 7) << 2);
}

// Ebc swizzle ([128][128] floats): bank window depends on BOTH low and high
// row bits so GEMM stores (rows 8-apart), U-pass (rows 1-apart) and output
// reads (rows 4-apart) all spread across 8 windows.
__device__ __forceinline__ int ebx(int b, int c) {
  return b * 128 + (c ^ (((b ^ (b >> 3)) & 7) << 2));
}

// ============ K1: projections (2 rows/block) + pb + pcx tail ================
// 288 blocks x 512 threads. ks = t>>7 (4-way k split), col = t&127.
__global__ __launch_bounds__(512) void k1(
    const float* __restrict__ Ha, const float* __restrict__ Hb,
    const float* __restrict__ Hc, const float* __restrict__ Wq,
    const float* __restrict__ Wk, const float* __restrict__ Wv,
    const float* __restrict__ fcw, float* __restrict__ ws) {
  __shared__ float part[4][2][128];
  __shared__ float rowsL[2][128];
  const int t   = threadIdx.x;
  const int r2  = blockIdx.x;               // 0..287
  const int ks  = t >> 7;
  const int col = t & 127;

  const float* X; const float* W; float* Y; int r;
  {
    const int row = r2 * 2;
    if (row < 64)       { X = Ha; W = Wq; Y = ws + OFF_Q;  r = row; }
    else if (row < 192) { X = Hb; W = Wk; Y = ws + OFF_KB; r = row - 64; }
    else if (row < 320) { X = Hc; W = Wk; Y = ws + OFF_KC; r = row - 192; }
    else if (row < 448) { X = Hb; W = Wv; Y = ws + OFF_VB; r = row - 320; }
    else                { X = Hc; W = Wv; Y = ws + OFF_VC; r = row - 448; }
  }
  const float* x0 = X + r * D_IN;
  const float* x1 = x0 + D_IN;
  const int i0 = ks * 64;
  float acc0 = 0.0f, acc1 = 0.0f;
  #pragma unroll 8
  for (int i = 0; i < 64; ++i) {
    const float w = W[(i0 + i) * DMODEL + col];
    acc0 = fmaf(x0[i0 + i], w, acc0);
    acc1 = fmaf(x1[i0 + i], w, acc1);
  }
  part[ks][0][col] = acc0;
  part[ks][1][col] = acc1;
  __syncthreads();
  if (ks == 0) {
    float f0 = 0.0f, f1 = 0.0f;
    #pragma unroll
    for (int k = 0; k < 4; ++k) { f0 += part[k][0][col]; f1 += part[k][1][col]; }
    Y[r * DMODEL + col]       = f0;
    Y[(r + 1) * DMODEL + col] = f1;
    rowsL[0][col] = f0;
    rowsL[1][col] = f1;
  }
  __syncthreads();

  const int row0 = r2 * 2;
  if (row0 >= 320 && row0 < 448) {
    // Vb rows: pb[b][h][kk], 2 rows x 16 (h,kk)
    if (t < 32) {
      const int lr = t >> 4, e = t & 15, hh = e >> 2, kk = e & 3;
      const int b = row0 - 320 + lr;
      float s = 0.0f;
      #pragma unroll
      for (int d = 0; d < D_H; ++d)
        s = fmaf(rowsL[lr][hh * D_H + d], fcw[kk * D_H + d], s);
      ws[OFF_PB + (b * 4 + hh) * 4 + kk] = s;
    }
  } else if (row0 >= 448) {
    // Vc rows: pcx[h][cc] with kk = cc&3, 2 rows x 4 h
    if (t < 8) {
      const int lr = t >> 2, hh = t & 3;
      const int cc = row0 - 448 + lr;
      const int kk = cc & 3;
      float s = 0.0f;
      #pragma unroll
      for (int d = 0; d < D_H; ++d)
        s = fmaf(rowsL[lr][hh * D_H + d], fcw[kk * D_H + d], s);
      ws[OFF_PC + hh * N_C + cc] = s;
    }
  }
}

// ============ K2: per-(a,h) block: E-scores + U + Z + output ================
__global__ __launch_bounds__(512) void k2(
    const float* __restrict__ ws, const float* __restrict__ fcb,
    float* __restrict__ out) {
  __shared__ float KbL[128 * 32];           // kswz [b][d]
  __shared__ float KcL[128 * 32];           // kswz [c][d]
  __shared__ float EbcL[128 * 128];         // ebx-swizzled [b][c]
  __shared__ float qaL[32];
  __shared__ float EabL[128], EacL[128], UL[128];
  __shared__ float pbL[128 * 4];            // pb slice [b][kk]
  __shared__ float pcxL[128];               // pcx slice [cc]
  __shared__ float red[4];

  const int t = threadIdx.x;
  const int a = blockIdx.x >> 2;
  const int h = blockIdx.x & 3;

  // --- stage: Kb/Kc h-slices, qa, pb, pcx ---
  {
    const int d = t & 31, r0 = t >> 5;      // r0 in [0,16)
    #pragma unroll
    for (int p = 0; p < 8; ++p) {
      const int r = r0 + p * 16;
      KbL[kswz(r, d)] = ws[OFF_KB + r * DMODEL + h * D_H + d];
      KcL[kswz(r, d)] = ws[OFF_KC + r * DMODEL + h * D_H + d];
    }
    if (t < 32) qaL[t] = ws[OFF_Q + a * DMODEL + h * D_H + t];
    pbL[t] = ws[OFF_PB + (t >> 2) * 16 + h * 4 + (t & 3)];
    if (t < 128) pcxL[t] = ws[OFF_PC + h * N_C + t];
  }
  __syncthreads();

  // --- Eab[b], Eac[c]: 4 threads per row ---
  {
    const int r = t >> 2, p = t & 3, d0 = p * 8;
    const float4 q0 = *(const float4*)&qaL[d0];
    const float4 q1 = *(const float4*)&qaL[d0 + 4];
    float4 x0 = *(const float4*)&KbL[kswz(r, d0)];
    float4 x1 = *(const float4*)&KbL[kswz(r, d0 + 4)];
    float s = dot4(q0, x0) + dot4(q1, x1);
    s += __shfl_xor(s, 1); s += __shfl_xor(s, 2);
    if (p == 0) EabL[r] = __expf(s * SCALE);
    x0 = *(const float4*)&KcL[kswz(r, d0)];
    x1 = *(const float4*)&KcL[kswz(r, d0 + 4)];
    s = dot4(q0, x0) + dot4(q1, x1);
    s += __shfl_xor(s, 1); s += __shfl_xor(s, 2);
    if (p == 0) EacL[r] = __expf(s * SCALE);
  }

  // --- Ebc plane: 8x8 tiles on t<256; wave spans 8 b-tiles x 8 c-tiles ---
  if (t < 256) {
    const int w  = t >> 6;                  // wave id 0..3
    const int bt = (t & 7) | ((w & 1) << 3);
    const int ct = ((t >> 3) & 7) | ((w >> 1) << 3);
    const int b0 = bt * 8, c0 = ct * 8;
    float acc[8][8];
    #pragma unroll
    for (int i = 0; i < 8; ++i)
      #pragma unroll
      for (int j = 0; j < 8; ++j) acc[i][j] = 0.0f;

    #pragma unroll
    for (int d0 = 0; d0 < 32; d0 += 4) {
      float4 cv[8];
      #pragma unroll
      for (int j = 0; j < 8; ++j) cv[j] = *(const float4*)&KcL[kswz(c0 + j, d0)];
      #pragma unroll
      for (int i = 0; i < 8; ++i) {
        const float4 bv = *(const float4*)&KbL[kswz(b0 + i, d0)];
        #pragma unroll
        for (int j = 0; j < 8; ++j) acc[i][j] += dot4(bv, cv[j]);
      }
    }
    #pragma unroll
    for (int i = 0; i < 8; ++i) {
      float4 lo, hi;
      lo.x = __expf(acc[i][0] * SCALE); lo.y = __expf(acc[i][1] * SCALE);
      lo.z = __expf(acc[i][2] * SCALE); lo.w = __expf(acc[i][3] * SCALE);
      hi.x = __expf(acc[i][4] * SCALE); hi.y = __expf(acc[i][5] * SCALE);
      hi.z = __expf(acc[i][6] * SCALE); hi.w = __expf(acc[i][7] * SCALE);
      *(float4*)&EbcL[ebx(b0 + i, c0)]     = lo;
      *(float4*)&EbcL[ebx(b0 + i, c0 + 4)] = hi;
    }
  }
  __syncthreads();

  // --- U[b] = sum_c Ebc[b][c]*Eac[c]: one thread per b ---
  if (t < 128) {
    float s = 0.0f;
    #pragma unroll 8
    for (int k = 0; k < 32; ++k) {
      const float4 e = *(const float4*)&EbcL[ebx(t, 4 * k)];
      const float4 v = *(const float4*)&EacL[4 * k];
      s += dot4(e, v);
    }
    UL[t] = s;
  }
  __syncthreads();

  // --- Z = sum_b Eab[b]*U[b] ---
  if (t < 128) {
    float v = EabL[t] * UL[t];
    #pragma unroll
    for (int o = 32; o > 0; o >>= 1) v += __shfl_down(v, o, 64);
    if ((t & 63) == 0) red[t >> 6] = v;
  }
  __syncthreads();
  if (t == 0) red[2] = 1.0f / (red[0] + red[1]);
  __syncthreads();
  const float zi = red[2];
  const float fb = fcb[0];

  // --- output: 1024 quads, 2 per thread ---
  #pragma unroll
  for (int q = 0; q < 2; ++q) {
    const int qid   = t + q * 512;          // < 1024
    const int b_loc = qid >> 5;             // 0..31
    const int c0v   = (qid & 31) * 4;       // 0..124
    const int b     = h * 32 + b_loc;
    const int bb    = (b_loc << 2) | (c0v >> 5);
    const int base0 = (c0v & 31) << 2;

    const float eabz = EabL[bb] * zi;
    const float4 pb4 = *(const float4*)&pbL[bb * 4];

    float rr[4];
    #pragma unroll
    for (int j = 0; j < 4; ++j) {
      const int bs = base0 + 4 * j;
      const float4 e4 = *(const float4*)&EbcL[ebx(bb, bs)];
      const float4 a4 = *(const float4*)&EacL[bs];
      const float4 x4 = *(const float4*)&pcxL[bs];
      float av = a4.x * (e4.x * (pb4.x + x4.x));
      av = fmaf(a4.y, e4.y * (pb4.y + x4.y), av);
      av = fmaf(a4.z, e4.z * (pb4.z + x4.z), av);
      av = fmaf(a4.w, e4.w * (pb4.w + x4.w), av);
      const float xj = fmaf(av, eabz, fb);
      rr[j] = 1.0f / (1.0f + __expf(-xj));
    }
    float4 res; res.x = rr[0]; res.y = rr[1]; res.z = rr[2]; res.w = rr[3];
    *(float4*)(out + a * (N_B * N_C) + b * N_C + c0v) = res;
  }
}

extern "C" void kernel_launch(void* const* d_in, const int* in_sizes, int n_in,
                              void* d_out, int out_size, void* d_ws, size_t ws_size,
                              hipStream_t stream) {
  const float* Ha  = (const float*)d_in[0];
  const float* Hb  = (const float*)d_in[1];
  const float* Hc  = (const float*)d_in[2];
  const float* Wq  = (const float*)d_in[3];
  const float* Wk  = (const float*)d_in[4];
  const float* Wv  = (const float*)d_in[5];
  const float* fcw = (const float*)d_in[6];
  const float* fcb = (const float*)d_in[7];
  float* out = (float*)d_out;
  float* ws  = (float*)d_ws;

  k1<<<288, 512, 0, stream>>>(Ha, Hb, Hc, Wq, Wk, Wv, fcw, ws);
  k2<<<256, 512, 0, stream>>>(ws, fcb, out);
}